// Round 1
// baseline (146.258 us; speedup 1.0000x reference)
//
#include <hip/hip_runtime.h>
#include <hip/hip_bf16.h>

#define NSEN 4000
#define NP   4096
#define DIN  128
#define DOUT 128
#define EDIM 16
#define BATCH 8
#define ROWS 16

typedef __attribute__((ext_vector_type(8))) short bf16x8;
typedef __attribute__((ext_vector_type(4))) float f32x4;

__device__ __forceinline__ unsigned short f2bf(float f) {
  unsigned int u = __float_as_uint(f);
  unsigned int r = (u + 0x7FFFu + ((u >> 16) & 1u)) >> 16;
  return (unsigned short)r;
}

__device__ __forceinline__ void gl_lds16(const void* g, void* l) {
  __builtin_amdgcn_global_load_lds((const __attribute__((address_space(1))) void*)g,
                                   (__attribute__((address_space(3))) void*)l, 16, 0, 0);
}

// ---------------- Kernel 1: adj = softmax(relu(E1 @ E2^T)) -> bf16, K-padded ----
__global__ __launch_bounds__(256) void k_adj(const float* __restrict__ E1,
                                             const float* __restrict__ E2,
                                             unsigned short* __restrict__ adjp) {
  __shared__ float e1s[ROWS][EDIM];
  __shared__ float red_m[ROWS][4], red_s[ROWS][4];
  __shared__ float fin_M[ROWS], fin_R[ROWS];
  const int tid = threadIdx.x;
  const int n0 = blockIdx.x * ROWS;
  // stage E1 rows (16x16 floats = 256 elements, one per thread)
  e1s[tid >> 4][tid & 15] = E1[(size_t)(n0 + (tid >> 4)) * EDIM + (tid & 15)];
  __syncthreads();

  float mx[ROWS], sm[ROWS];
#pragma unroll
  for (int r = 0; r < ROWS; r++) { mx[r] = 0.f; sm[r] = 0.f; }

  // Pass A: online max/sum, two columns per iteration to amortize e1 LDS reads
  for (int m = tid; m < NSEN; m += 512) {
    const int mB = m + 256;
    const bool hasB = (mB < NSEN);
    float e2a[16], e2b[16];
    {
      const float4* p = (const float4*)&E2[(size_t)m * EDIM];
      *(float4*)&e2a[0] = p[0]; *(float4*)&e2a[4] = p[1];
      *(float4*)&e2a[8] = p[2]; *(float4*)&e2a[12] = p[3];
    }
    if (hasB) {
      const float4* p = (const float4*)&E2[(size_t)mB * EDIM];
      *(float4*)&e2b[0] = p[0]; *(float4*)&e2b[4] = p[1];
      *(float4*)&e2b[8] = p[2]; *(float4*)&e2b[12] = p[3];
    }
#pragma unroll
    for (int r = 0; r < ROWS; r++) {
      const float4* e1v = (const float4*)e1s[r];
      float sa = 0.f, sb = 0.f;
#pragma unroll
      for (int kq = 0; kq < 4; kq++) {
        float4 e = e1v[kq];
        sa = fmaf(e.x, e2a[kq*4+0], sa); sa = fmaf(e.y, e2a[kq*4+1], sa);
        sa = fmaf(e.z, e2a[kq*4+2], sa); sa = fmaf(e.w, e2a[kq*4+3], sa);
        if (hasB) {
          sb = fmaf(e.x, e2b[kq*4+0], sb); sb = fmaf(e.y, e2b[kq*4+1], sb);
          sb = fmaf(e.z, e2b[kq*4+2], sb); sb = fmaf(e.w, e2b[kq*4+3], sb);
        }
      }
      float la = fmaxf(sa, 0.f);
      float nm = fmaxf(mx[r], la);
      sm[r] = sm[r] * __expf(mx[r] - nm) + __expf(la - nm);
      mx[r] = nm;
      if (hasB) {
        float lb = fmaxf(sb, 0.f);
        float nm2 = fmaxf(mx[r], lb);
        sm[r] = sm[r] * __expf(mx[r] - nm2) + __expf(lb - nm2);
        mx[r] = nm2;
      }
    }
  }
  // wave butterfly reduce (64 lanes)
#pragma unroll
  for (int r = 0; r < ROWS; r++) {
    for (int off = 1; off < 64; off <<= 1) {
      float om = __shfl_xor(mx[r], off, 64);
      float os = __shfl_xor(sm[r], off, 64);
      float nm = fmaxf(mx[r], om);
      sm[r] = sm[r] * __expf(mx[r] - nm) + os * __expf(om - nm);
      mx[r] = nm;
    }
  }
  const int lane = tid & 63, wv = tid >> 6;
  if (lane == 0) {
#pragma unroll
    for (int r = 0; r < ROWS; r++) { red_m[r][wv] = mx[r]; red_s[r][wv] = sm[r]; }
  }
  __syncthreads();
  if (tid < ROWS) {
    float M = red_m[tid][0], S = red_s[tid][0];
#pragma unroll
    for (int w = 1; w < 4; w++) {
      float om = red_m[tid][w], os = red_s[tid][w];
      float nm = fmaxf(M, om);
      S = S * __expf(M - nm) + os * __expf(om - nm);
      M = nm;
    }
    fin_M[tid] = M;
    fin_R[tid] = 1.f / S;
  }
  __syncthreads();

  // Pass B: recompute, normalize, write bf16 (cols >= NSEN written as 0)
  for (int m = tid; m < NP; m += 256) {
    if (m < NSEN) {
      float e2r[16];
      const float4* p = (const float4*)&E2[(size_t)m * EDIM];
      *(float4*)&e2r[0] = p[0]; *(float4*)&e2r[4] = p[1];
      *(float4*)&e2r[8] = p[2]; *(float4*)&e2r[12] = p[3];
#pragma unroll
      for (int r = 0; r < ROWS; r++) {
        const float4* e1v = (const float4*)e1s[r];
        float s = 0.f;
#pragma unroll
        for (int kq = 0; kq < 4; kq++) {
          float4 e = e1v[kq];
          s = fmaf(e.x, e2r[kq*4+0], s); s = fmaf(e.y, e2r[kq*4+1], s);
          s = fmaf(e.z, e2r[kq*4+2], s); s = fmaf(e.w, e2r[kq*4+3], s);
        }
        float l = fmaxf(s, 0.f);
        float w = __expf(l - fin_M[r]) * fin_R[r];
        adjp[(size_t)(n0 + r) * NP + m] = f2bf(w);
      }
    } else {
#pragma unroll
      for (int r = 0; r < ROWS; r++) adjp[(size_t)(n0 + r) * NP + m] = 0;
    }
  }
}

// ---------------- Kernel 2: xpt[b*128+f][m] = bf16(x[b][m][f]), rows m>=NSEN -> 0
__global__ __launch_bounds__(256) void k_xpt(const float* __restrict__ x,
                                             unsigned short* __restrict__ xpt) {
  __shared__ unsigned short tile[64][72];  // [f_local][m_local], padded
  const int t = threadIdx.x;
  const int m0 = blockIdx.x * 64;
  const int f0 = blockIdx.y * 64;
  const int b  = blockIdx.z;
  const int f4 = t & 15, mrow = t >> 4;
#pragma unroll
  for (int rep = 0; rep < 4; rep++) {
    int ml = mrow + rep * 16;
    int m = m0 + ml;
    float4 v = make_float4(0.f, 0.f, 0.f, 0.f);
    if (m < NSEN) v = *(const float4*)&x[((size_t)b * NSEN + m) * DIN + f0 + f4 * 4];
    tile[f4*4+0][ml] = f2bf(v.x);
    tile[f4*4+1][ml] = f2bf(v.y);
    tile[f4*4+2][ml] = f2bf(v.z);
    tile[f4*4+3][ml] = f2bf(v.w);
  }
  __syncthreads();
  const int seg = t & 7, fl0 = t >> 3;
#pragma unroll
  for (int it = 0; it < 2; it++) {
    int fl = fl0 + it * 32;
    int j = b * DIN + f0 + fl;
    uint4 v = *(const uint4*)&tile[fl][seg * 8];
    *(uint4*)&xpt[(size_t)j * NP + m0 + seg * 8] = v;
  }
}

// ---------------- Kernel 2b: Wt[o][f] = bf16(W[f][o]) ---------------------------
__global__ __launch_bounds__(256) void k_wt(const float* __restrict__ W,
                                            unsigned short* __restrict__ Wt) {
  int idx = blockIdx.x * 256 + threadIdx.x;  // 16384 total
  int o = idx >> 7, f = idx & 127;
  Wt[idx] = f2bf(W[(size_t)f * DOUT + o]);
}

// ---------------- Kernel 3: agg = adj @ x  (bf16 MFMA, 128x128 tile, BK=32) -----
// A = adjp [4096][4096] bf16 (rows>=4000 garbage, masked at store; cols>=4000 zero)
// Bt = xpt [1024][4096] bf16 (B^T layout)
// out: aggb [b][n][f] bf16
__global__ __launch_bounds__(256) void k_gemm1(const unsigned short* __restrict__ A,
                                               const unsigned short* __restrict__ Bt,
                                               unsigned short* __restrict__ aggb) {
  __shared__ unsigned short tA[128 * 32];
  __shared__ unsigned short tB[128 * 32];
  const int tid = threadIdx.x;
  const int lane = tid & 63, wv = tid >> 6;
  const int wr = wv >> 1, wc = wv & 1;
  const int lr = lane & 15, lq = lane >> 4;
  const int m0 = blockIdx.y * 128;
  const int c0 = blockIdx.x * 128;

  f32x4 acc[4][4];
#pragma unroll
  for (int p = 0; p < 4; p++)
#pragma unroll
    for (int q = 0; q < 4; q++) acc[p][q] = (f32x4){0.f, 0.f, 0.f, 0.f};

  for (int kb = 0; kb < NP; kb += 32) {
#pragma unroll
    for (int i = 0; i < 2; i++) {
      int s = wv * 2 + i;
      int f = s * 64 + lane;
      int row = f >> 2, kc = (f & 3) * 8;
      gl_lds16(&A[(size_t)(m0 + row) * NP + kb + kc], &tA[s * 512]);
      gl_lds16(&Bt[(size_t)(c0 + row) * NP + kb + kc], &tB[s * 512]);
    }
    __syncthreads();
    bf16x8 af[4], bf[4];
#pragma unroll
    for (int p = 0; p < 4; p++)
      af[p] = *(const bf16x8*)&tA[(wr * 64 + p * 16 + lr) * 32 + lq * 8];
#pragma unroll
    for (int q = 0; q < 4; q++)
      bf[q] = *(const bf16x8*)&tB[(wc * 64 + q * 16 + lr) * 32 + lq * 8];
#pragma unroll
    for (int p = 0; p < 4; p++)
#pragma unroll
      for (int q = 0; q < 4; q++)
        acc[p][q] = __builtin_amdgcn_mfma_f32_16x16x32_bf16(af[p], bf[q], acc[p][q], 0, 0, 0);
    __syncthreads();
  }
  // epilogue: store bf16 into aggb[b][n][f]; mask padded rows
#pragma unroll
  for (int p = 0; p < 4; p++) {
    int nbase = m0 + wr * 64 + p * 16 + lq * 4;
#pragma unroll
    for (int q = 0; q < 4; q++) {
      int j = c0 + wc * 64 + q * 16 + lr;  // global col = b*128 + f
      int b = j >> 7, fcol = j & 127;
#pragma unroll
      for (int i = 0; i < 4; i++) {
        int nn = nbase + i;
        if (nn < NSEN)
          aggb[((size_t)b * NSEN + nn) * DIN + fcol] = f2bf(acc[p][q][i]);
      }
    }
  }
}

// ---------------- Kernel 4: out = relu(agg @ W + b)  (f32 out) -------------------
__global__ __launch_bounds__(256) void k_gemm2(const unsigned short* __restrict__ A,
                                               const unsigned short* __restrict__ Wt,
                                               const float* __restrict__ bias,
                                               float* __restrict__ out) {
  __shared__ unsigned short tA[4][128 * 32];
  __shared__ unsigned short tW[4][128 * 32];
  const int tid = threadIdx.x;
  const int lane = tid & 63, wv = tid >> 6;
  const int wr = wv >> 1, wc = wv & 1;
  const int lr = lane & 15, lq = lane >> 4;
  const size_t r0 = (size_t)blockIdx.x * 128;

#pragma unroll
  for (int ks = 0; ks < 4; ks++) {
#pragma unroll
    for (int i = 0; i < 2; i++) {
      int s = wv * 2 + i;
      int f = s * 64 + lane;
      int row = f >> 2, kc = (f & 3) * 8;
      gl_lds16(&A[(r0 + row) * DIN + ks * 32 + kc], &tA[ks][s * 512]);
      gl_lds16(&Wt[(size_t)row * DIN + ks * 32 + kc], &tW[ks][s * 512]);
    }
  }
  __syncthreads();

  f32x4 acc[4][4];
#pragma unroll
  for (int p = 0; p < 4; p++)
#pragma unroll
    for (int q = 0; q < 4; q++) acc[p][q] = (f32x4){0.f, 0.f, 0.f, 0.f};

#pragma unroll
  for (int ks = 0; ks < 4; ks++) {
    bf16x8 af[4], bf[4];
#pragma unroll
    for (int p = 0; p < 4; p++)
      af[p] = *(const bf16x8*)&tA[ks][(wr * 64 + p * 16 + lr) * 32 + lq * 8];
#pragma unroll
    for (int q = 0; q < 4; q++)
      bf[q] = *(const bf16x8*)&tW[ks][(wc * 64 + q * 16 + lr) * 32 + lq * 8];
#pragma unroll
    for (int p = 0; p < 4; p++)
#pragma unroll
      for (int q = 0; q < 4; q++)
        acc[p][q] = __builtin_amdgcn_mfma_f32_16x16x32_bf16(af[p], bf[q], acc[p][q], 0, 0, 0);
  }
#pragma unroll
  for (int p = 0; p < 4; p++)
#pragma unroll
    for (int q = 0; q < 4; q++) {
      int col = wc * 64 + q * 16 + lr;
      float bb = bias[col];
#pragma unroll
      for (int i = 0; i < 4; i++) {
        int row = wr * 64 + p * 16 + lq * 4 + i;
        float v = acc[p][q][i] + bb;
        out[(r0 + row) * DOUT + col] = fmaxf(v, 0.f);
      }
    }
}

// ---------------- launch ---------------------------------------------------------
extern "C" void kernel_launch(void* const* d_in, const int* in_sizes, int n_in,
                              void* d_out, int out_size, void* d_ws, size_t ws_size,
                              hipStream_t stream) {
  const float* x    = (const float*)d_in[0];
  const float* E1   = (const float*)d_in[1];
  const float* E2   = (const float*)d_in[2];
  const float* W    = (const float*)d_in[3];
  const float* bias = (const float*)d_in[4];
  float* out = (float*)d_out;

  char* ws = (char*)d_ws;
  // layout (bytes): adjp 33554432 | xpt 8388608 | Wt 32768 | aggb 8192000  (~48 MiB)
  unsigned short* adjp = (unsigned short*)(ws);
  unsigned short* xpt  = (unsigned short*)(ws + 33554432);
  unsigned short* wt   = (unsigned short*)(ws + 33554432 + 8388608);
  unsigned short* aggb = (unsigned short*)(ws + 33554432 + 8388608 + 32768);

  k_adj<<<dim3(NSEN / ROWS), dim3(256), 0, stream>>>(E1, E2, adjp);
  k_xpt<<<dim3(NP / 64, DIN / 64, BATCH), dim3(256), 0, stream>>>(x, xpt);
  k_wt<<<dim3(64), dim3(256), 0, stream>>>(W, wt);
  k_gemm1<<<dim3(BATCH * DIN / 128, NP / 128), dim3(256), 0, stream>>>(adjp, xpt, aggb);
  k_gemm2<<<dim3(BATCH * NSEN * DIN / (128 * DOUT)), dim3(256), 0, stream>>>(aggb, wt, bias, out);
}

// Round 2
// 134.198 us; speedup vs baseline: 1.0899x; 1.0899x over previous
//
#include <hip/hip_runtime.h>
#include <hip/hip_bf16.h>

#define NSEN 4000
#define NP   4096
#define DIN  128
#define DOUT 128
#define EDIM 16
#define BATCH 8

typedef __attribute__((ext_vector_type(8))) short bf16x8;
typedef __attribute__((ext_vector_type(4))) float f32x4;

__device__ __forceinline__ unsigned short f2bf(float f) {
  unsigned int u = __float_as_uint(f);
  unsigned int r = (u + 0x7FFFu + ((u >> 16) & 1u)) >> 16;
  return (unsigned short)r;
}

__device__ __forceinline__ void gl_lds16(const void* g, void* l) {
  __builtin_amdgcn_global_load_lds((const __attribute__((address_space(1))) void*)g,
                                   (__attribute__((address_space(3))) void*)l, 16, 0, 0);
}

// ---------------- Kernel 1: P = exp(relu(E1 @ E2^T)) unnormalized -> bf16; rinv[n] = 1/rowsum
// No max-subtraction: logits = 16-dim dots of N(0,1) => |l| <~ 25, exp fits fp32 easily.
__global__ __launch_bounds__(256) void k_adj(const float* __restrict__ E1,
                                             const float* __restrict__ E2,
                                             unsigned short* __restrict__ adjp,
                                             float* __restrict__ rinv) {
  __shared__ float e1s[16][16];
  const int tid = threadIdx.x;
  const int n0 = blockIdx.x * 16;
  e1s[tid >> 4][tid & 15] = E1[(size_t)(n0 + (tid >> 4)) * EDIM + (tid & 15)];
  __syncthreads();
  const int lane = tid & 63, wv = tid >> 6;  // wave wv owns rows n0+wv*4 .. +3

  float e1r[4][16];
#pragma unroll
  for (int r = 0; r < 4; r++)
#pragma unroll
    for (int k = 0; k < 4; k++)
      *(float4*)&e1r[r][k * 4] = *(const float4*)&e1s[wv * 4 + r][k * 4];

  float rs[4] = {0.f, 0.f, 0.f, 0.f};
#pragma unroll 2
  for (int sw = 0; sw < 8; sw++) {
    const int mb = sw * 512 + lane * 8;
    bf16x8 pk[4];
#pragma unroll
    for (int j = 0; j < 8; j++) {
      const int m = mb + j;
      float e2r[16];
      if (m < NSEN) {
        const float4* p4 = (const float4*)&E2[(size_t)m * EDIM];
        *(float4*)&e2r[0] = p4[0]; *(float4*)&e2r[4] = p4[1];
        *(float4*)&e2r[8] = p4[2]; *(float4*)&e2r[12] = p4[3];
      } else {
#pragma unroll
        for (int k = 0; k < 16; k++) e2r[k] = 0.f;
      }
#pragma unroll
      for (int r = 0; r < 4; r++) {
        float s = 0.f;
#pragma unroll
        for (int k = 0; k < 16; k++) s = fmaf(e1r[r][k], e2r[k], s);
        float p = (m < NSEN) ? __expf(fmaxf(s, 0.f)) : 0.f;
        rs[r] += p;
        pk[r][j] = (short)f2bf(p);
      }
    }
#pragma unroll
    for (int r = 0; r < 4; r++)
      *(bf16x8*)&adjp[(size_t)(n0 + wv * 4 + r) * NP + mb] = pk[r];
  }
  // reduce rowsums across the 64 lanes
#pragma unroll
  for (int r = 0; r < 4; r++) {
#pragma unroll
    for (int off = 1; off < 64; off <<= 1) rs[r] += __shfl_xor(rs[r], off, 64);
  }
  if (lane == 0) {
#pragma unroll
    for (int r = 0; r < 4; r++) rinv[n0 + wv * 4 + r] = 1.0f / rs[r];
  }
}

// ---------------- Kernel 2: xpt[b*128+f][m] = bf16(x[b][m][f]), cols m>=NSEN -> 0
__global__ __launch_bounds__(256) void k_xpt(const float* __restrict__ x,
                                             unsigned short* __restrict__ xpt) {
  __shared__ unsigned short tile[64][72];
  const int t = threadIdx.x;
  const int m0 = blockIdx.x * 64;
  const int f0 = blockIdx.y * 64;
  const int b  = blockIdx.z;
  const int f4 = t & 15, mrow = t >> 4;
#pragma unroll
  for (int rep = 0; rep < 4; rep++) {
    int ml = mrow + rep * 16;
    int m = m0 + ml;
    float4 v = make_float4(0.f, 0.f, 0.f, 0.f);
    if (m < NSEN) v = *(const float4*)&x[((size_t)b * NSEN + m) * DIN + f0 + f4 * 4];
    tile[f4*4+0][ml] = f2bf(v.x);
    tile[f4*4+1][ml] = f2bf(v.y);
    tile[f4*4+2][ml] = f2bf(v.z);
    tile[f4*4+3][ml] = f2bf(v.w);
  }
  __syncthreads();
  const int seg = t & 7, fl0 = t >> 3;
#pragma unroll
  for (int it = 0; it < 2; it++) {
    int fl = fl0 + it * 32;
    int j = b * DIN + f0 + fl;
    uint4 v = *(const uint4*)&tile[fl][seg * 8];
    *(uint4*)&xpt[(size_t)j * NP + m0 + seg * 8] = v;
  }
}

// ---------------- Kernel 2b: Wt[o][f] = bf16(W[f][o]) ---------------------------
__global__ __launch_bounds__(256) void k_wt(const float* __restrict__ W,
                                            unsigned short* __restrict__ Wt) {
  int idx = blockIdx.x * 256 + threadIdx.x;  // 16384 total
  int o = idx >> 7, f = idx & 127;
  Wt[idx] = f2bf(W[(size_t)f * DOUT + o]);
}

// ---------------- Kernel 3: fused  out = relu(((P @ x) * rinv) @ W + bias) ------
// Main loop: 128x128 tile, BK=64, double-buffered global_load_lds prefetch,
// XOR-swizzled LDS (pre-swizzled global source, rule #21).
// Epilogue: normalize rows, restage tile as bf16 in LDS, second MFMA vs W-frags
// in registers, bias+relu, store f32.
__global__ __launch_bounds__(256, 1) void k_gemm1(const unsigned short* __restrict__ A,
                                                  const unsigned short* __restrict__ Bt,
                                                  const unsigned short* __restrict__ Wt,
                                                  const float* __restrict__ rinv,
                                                  const float* __restrict__ bias,
                                                  float* __restrict__ out) {
  __shared__ __align__(16) unsigned short tA[2][128 * 64];
  __shared__ __align__(16) unsigned short tB[2][128 * 64];
  __shared__ __align__(16) unsigned short eps[128 * 136];
  const int tid = threadIdx.x;
  const int lane = tid & 63, wv = tid >> 6;
  const int wr = wv >> 1, wc = wv & 1;
  const int lr = lane & 15, lq = lane >> 4;
  const int b  = blockIdx.x;        // batch (grid.x==8 -> pinned per XCD)
  const int m0 = blockIdx.y * 128;  // node-row tile
  const int c0 = b * 128;           // row base in Bt (= b*DIN + f)

  f32x4 acc[4][4];
#pragma unroll
  for (int p = 0; p < 4; p++)
#pragma unroll
    for (int q = 0; q < 4; q++) acc[p][q] = (f32x4){0.f, 0.f, 0.f, 0.f};

  // staging: 4 chunks of 16B per thread per tile; source col pre-swizzled
  // lin short-dest = idx*8 ; row = idx>>3 ; dest chunk = idx&7 ; src chunk = (idx&7)^(row&7)
#define STAGE(bufi, kb)                                                          \
  {                                                                              \
    _Pragma("unroll")                                                            \
    for (int s = 0; s < 4; s++) {                                                \
      int idx = s * 256 + tid;                                                   \
      int row = idx >> 3;                                                        \
      int kc = ((idx & 7) ^ (row & 7)) << 3;                                     \
      gl_lds16(&A[(size_t)(m0 + row) * NP + (kb) + kc], &tA[bufi][idx * 8]);     \
      gl_lds16(&Bt[(size_t)(c0 + row) * NP + (kb) + kc], &tB[bufi][idx * 8]);    \
    }                                                                            \
  }

  STAGE(0, 0);
  __syncthreads();

  for (int it = 0; it < 64; it++) {
    const int cur = it & 1;
    if (it < 63) STAGE(cur ^ 1, (it + 1) * 64);
    bf16x8 af[2][4], bfr[2][4];
#pragma unroll
    for (int sk = 0; sk < 2; sk++) {
      const int koff = (sk * 32 + lq * 8) ^ ((lr & 7) << 3);
#pragma unroll
      for (int p = 0; p < 4; p++)
        af[sk][p] = *(const bf16x8*)&tA[cur][(wr * 64 + p * 16 + lr) * 64 + koff];
#pragma unroll
      for (int q = 0; q < 4; q++)
        bfr[sk][q] = *(const bf16x8*)&tB[cur][(wc * 64 + q * 16 + lr) * 64 + koff];
    }
#pragma unroll
    for (int sk = 0; sk < 2; sk++)
#pragma unroll
      for (int p = 0; p < 4; p++)
#pragma unroll
        for (int q = 0; q < 4; q++)
          acc[p][q] = __builtin_amdgcn_mfma_f32_16x16x32_bf16(af[sk][p], bfr[sk][q], acc[p][q], 0, 0, 0);
    __syncthreads();  // drains vmcnt for next buffer + protects LDS reuse
  }
#undef STAGE

  // ---- fused epilogue: agg = acc * rinv[row]  ->  out = relu(agg @ W + bias) ----
  // W fragments from global (tiny, L2/L3-hot)
  bf16x8 wf[4][4];  // [q][ks]
#pragma unroll
  for (int q = 0; q < 4; q++)
#pragma unroll
    for (int ks = 0; ks < 4; ks++)
      wf[q][ks] = *(const bf16x8*)&Wt[(size_t)(wc * 64 + q * 16 + lr) * DIN + ks * 32 + lq * 8];

  // normalize + convert + restage (eps: [128][136] bf16, +8 pad spreads banks)
#pragma unroll
  for (int p = 0; p < 4; p++) {
    float rv[4];
#pragma unroll
    for (int i = 0; i < 4; i++)
      rv[i] = rinv[m0 + wr * 64 + p * 16 + lq * 4 + i];
#pragma unroll
    for (int q = 0; q < 4; q++)
#pragma unroll
      for (int i = 0; i < 4; i++)
        eps[(wr * 64 + p * 16 + lq * 4 + i) * 136 + wc * 64 + q * 16 + lr] =
            f2bf(acc[p][q][i] * rv[i]);
  }
  __syncthreads();

  f32x4 acc2[4][4];
#pragma unroll
  for (int p = 0; p < 4; p++)
#pragma unroll
    for (int q = 0; q < 4; q++) acc2[p][q] = (f32x4){0.f, 0.f, 0.f, 0.f};

#pragma unroll
  for (int ks = 0; ks < 4; ks++) {
    bf16x8 a2[4];
#pragma unroll
    for (int p = 0; p < 4; p++)
      a2[p] = *(const bf16x8*)&eps[(wr * 64 + p * 16 + lr) * 136 + ks * 32 + lq * 8];
#pragma unroll
    for (int p = 0; p < 4; p++)
#pragma unroll
      for (int q = 0; q < 4; q++)
        acc2[p][q] = __builtin_amdgcn_mfma_f32_16x16x32_bf16(a2[p], wf[q][ks], acc2[p][q], 0, 0, 0);
  }

#pragma unroll
  for (int p = 0; p < 4; p++)
#pragma unroll
    for (int q = 0; q < 4; q++) {
      const int o = wc * 64 + q * 16 + lr;
      const float bb = bias[o];
#pragma unroll
      for (int i = 0; i < 4; i++) {
        const int n = m0 + wr * 64 + p * 16 + lq * 4 + i;
        if (n < NSEN)
          out[((size_t)b * NSEN + n) * DOUT + o] = fmaxf(acc2[p][q][i] + bb, 0.f);
      }
    }
}

// ---------------- launch ---------------------------------------------------------
extern "C" void kernel_launch(void* const* d_in, const int* in_sizes, int n_in,
                              void* d_out, int out_size, void* d_ws, size_t ws_size,
                              hipStream_t stream) {
  const float* x    = (const float*)d_in[0];
  const float* E1   = (const float*)d_in[1];
  const float* E2   = (const float*)d_in[2];
  const float* W    = (const float*)d_in[3];
  const float* bias = (const float*)d_in[4];
  float* out = (float*)d_out;

  char* ws = (char*)d_ws;
  // layout: adjp 33554432 | xpt 8388608 | Wt 32768 | rinv 16384  (~42 MiB)
  unsigned short* adjp = (unsigned short*)(ws);
  unsigned short* xpt  = (unsigned short*)(ws + 33554432);
  unsigned short* wt   = (unsigned short*)(ws + 33554432 + 8388608);
  float*          rinv = (float*)(ws + 33554432 + 8388608 + 32768);

  k_adj<<<dim3(NSEN / 16), dim3(256), 0, stream>>>(E1, E2, adjp, rinv);
  k_xpt<<<dim3(NP / 64, DIN / 64, BATCH), dim3(256), 0, stream>>>(x, xpt);
  k_wt<<<dim3(64), dim3(256), 0, stream>>>(W, wt);
  k_gemm1<<<dim3(BATCH, NP / 128), dim3(256), 0, stream>>>(adjp, xpt, wt, rinv, bias, out);
}

// Round 3
// 120.496 us; speedup vs baseline: 1.2138x; 1.1137x over previous
//
#include <hip/hip_runtime.h>
#include <hip/hip_bf16.h>

#define NSEN 4000
#define NP   4096
#define DIN  128
#define DOUT 128
#define EDIM 16
#define BATCH 8

typedef __attribute__((ext_vector_type(8))) short bf16x8;
typedef __attribute__((ext_vector_type(4))) float f32x4;

__device__ __forceinline__ unsigned short f2bf(float f) {
  unsigned int u = __float_as_uint(f);
  unsigned int r = (u + 0x7FFFu + ((u >> 16) & 1u)) >> 16;
  return (unsigned short)r;
}

__device__ __forceinline__ void gl_lds16(const void* g, void* l) {
  __builtin_amdgcn_global_load_lds((const __attribute__((address_space(1))) void*)g,
                                   (__attribute__((address_space(3))) void*)l, 16, 0, 0);
}

// ---------------- Kernel 1: P = exp(relu(E1 @ E2^T)) unnorm -> bf16; rinv = 1/rowsum
// block NSEN/16 does the (tiny) W transpose instead (merged to save a launch).
__global__ __launch_bounds__(256) void k_adj(const float* __restrict__ E1,
                                             const float* __restrict__ E2,
                                             const float* __restrict__ W,
                                             unsigned short* __restrict__ adjp,
                                             float* __restrict__ rinv,
                                             unsigned short* __restrict__ Wt) {
  if (blockIdx.x == NSEN / 16) {
    for (int i = threadIdx.x; i < DIN * DOUT; i += 256) {
      int o = i >> 7, f = i & 127;
      Wt[i] = f2bf(W[(size_t)f * DOUT + o]);
    }
    return;
  }
  __shared__ float e1s[16][16];
  const int tid = threadIdx.x;
  const int n0 = blockIdx.x * 16;
  e1s[tid >> 4][tid & 15] = E1[(size_t)(n0 + (tid >> 4)) * EDIM + (tid & 15)];
  __syncthreads();
  const int lane = tid & 63, wv = tid >> 6;  // wave wv owns rows n0+wv*4 .. +3

  float e1r[4][16];
#pragma unroll
  for (int r = 0; r < 4; r++)
#pragma unroll
    for (int k = 0; k < 4; k++)
      *(float4*)&e1r[r][k * 4] = *(const float4*)&e1s[wv * 4 + r][k * 4];

  float rs[4] = {0.f, 0.f, 0.f, 0.f};
#pragma unroll 2
  for (int sw = 0; sw < 8; sw++) {
    const int mb = sw * 512 + lane * 8;
    bf16x8 pk[4];
#pragma unroll
    for (int j = 0; j < 8; j++) {
      const int m = mb + j;
      float e2r[16];
      if (m < NSEN) {
        const float4* p4 = (const float4*)&E2[(size_t)m * EDIM];
        *(float4*)&e2r[0] = p4[0]; *(float4*)&e2r[4] = p4[1];
        *(float4*)&e2r[8] = p4[2]; *(float4*)&e2r[12] = p4[3];
      } else {
#pragma unroll
        for (int k = 0; k < 16; k++) e2r[k] = 0.f;
      }
#pragma unroll
      for (int r = 0; r < 4; r++) {
        float s = 0.f;
#pragma unroll
        for (int k = 0; k < 16; k++) s = fmaf(e1r[r][k], e2r[k], s);
        float p = (m < NSEN) ? __expf(fmaxf(s, 0.f)) : 0.f;
        rs[r] += p;
        pk[r][j] = (short)f2bf(p);
      }
    }
#pragma unroll
    for (int r = 0; r < 4; r++)
      *(bf16x8*)&adjp[(size_t)(n0 + wv * 4 + r) * NP + mb] = pk[r];
  }
#pragma unroll
  for (int r = 0; r < 4; r++) {
#pragma unroll
    for (int off = 1; off < 64; off <<= 1) rs[r] += __shfl_xor(rs[r], off, 64);
  }
  if (lane == 0) {
#pragma unroll
    for (int r = 0; r < 4; r++) rinv[n0 + wv * 4 + r] = 1.0f / rs[r];
  }
}

// ---------------- Kernel 2: xpt[b*128+f][m] = bf16(x[b][m][f]), cols m>=NSEN -> 0
__global__ __launch_bounds__(256) void k_xpt(const float* __restrict__ x,
                                             unsigned short* __restrict__ xpt) {
  __shared__ unsigned short tile[64][72];
  const int t = threadIdx.x;
  const int m0 = blockIdx.x * 64;
  const int f0 = blockIdx.y * 64;
  const int b  = blockIdx.z;
  const int f4 = t & 15, mrow = t >> 4;
#pragma unroll
  for (int rep = 0; rep < 4; rep++) {
    int ml = mrow + rep * 16;
    int m = m0 + ml;
    float4 v = make_float4(0.f, 0.f, 0.f, 0.f);
    if (m < NSEN) v = *(const float4*)&x[((size_t)b * NSEN + m) * DIN + f0 + f4 * 4];
    tile[f4*4+0][ml] = f2bf(v.x);
    tile[f4*4+1][ml] = f2bf(v.y);
    tile[f4*4+2][ml] = f2bf(v.z);
    tile[f4*4+3][ml] = f2bf(v.w);
  }
  __syncthreads();
  const int seg = t & 7, fl0 = t >> 3;
#pragma unroll
  for (int it = 0; it < 2; it++) {
    int fl = fl0 + it * 32;
    int j = b * DIN + f0 + fl;
    uint4 v = *(const uint4*)&tile[fl][seg * 8];
    *(uint4*)&xpt[(size_t)j * NP + m0 + seg * 8] = v;
  }
}

// ---------------- Kernel 3: fused  out = relu(((P @ x) * rinv) @ W + bias) ------
// 128x128 tile, BK=64, 3-buffer depth-2 prefetch with COUNTED vmcnt (T3+T4),
// raw s_barrier (no vmcnt(0) drain mid-loop), setprio around MFMA (T5),
// XOR-swizzled LDS via pre-swizzled global source (rule #21).
__global__ __launch_bounds__(256, 2) void k_gemm1(const unsigned short* __restrict__ A,
                                                  const unsigned short* __restrict__ Bt,
                                                  const unsigned short* __restrict__ Wt,
                                                  const float* __restrict__ rinv,
                                                  const float* __restrict__ bias,
                                                  float* __restrict__ out) {
  __shared__ __align__(16) unsigned short tA[3][128 * 64];
  __shared__ __align__(16) unsigned short tB[3][128 * 64];
  const int tid = threadIdx.x;
  const int lane = tid & 63, wv = tid >> 6;
  const int wr = wv >> 1, wc = wv & 1;
  const int lr = lane & 15, lq = lane >> 4;
  const int m0 = blockIdx.x * 128;  // x-major: linear id % 8 = m-tile % 8 -> same-m0 cohort shares XCD L2
  const int b  = blockIdx.y;
  const int c0 = b * 128;

  f32x4 acc[4][4];
#pragma unroll
  for (int p = 0; p < 4; p++)
#pragma unroll
    for (int q = 0; q < 4; q++) acc[p][q] = (f32x4){0.f, 0.f, 0.f, 0.f};

  // 8 gl_lds16 per thread per STAGE (4 A + 4 B); source k-chunk pre-swizzled
#define STAGE(bufi, kb)                                                          \
  {                                                                              \
    _Pragma("unroll")                                                            \
    for (int s = 0; s < 4; s++) {                                                \
      int idx = s * 256 + tid;                                                   \
      int row = idx >> 3;                                                        \
      int kc = ((idx & 7) ^ (row & 7)) << 3;                                     \
      gl_lds16(&A[(size_t)(m0 + row) * NP + (kb) + kc], &tA[bufi][idx * 8]);     \
      gl_lds16(&Bt[(size_t)(c0 + row) * NP + (kb) + kc], &tB[bufi][idx * 8]);    \
    }                                                                            \
  }

  STAGE(0, 0);
  STAGE(1, 64);

  int cur = 0;
  for (int it = 0; it < 64; ++it) {
    if (it < 62) {
      int nb = cur + 2; if (nb >= 3) nb -= 3;
      STAGE(nb, (it + 2) * 64);
      asm volatile("s_waitcnt vmcnt(16)" ::: "memory");  // cur's 8 landed; 16 stay in flight
    } else if (it == 62) {
      asm volatile("s_waitcnt vmcnt(8)" ::: "memory");
    } else {
      asm volatile("s_waitcnt vmcnt(0)" ::: "memory");
    }
    __builtin_amdgcn_s_barrier();  // all waves' cur tile staged

    bf16x8 af[2][4], bfr[2][4];
#pragma unroll
    for (int sk = 0; sk < 2; sk++) {
      const int koff = (sk * 32 + lq * 8) ^ ((lr & 7) << 3);
#pragma unroll
      for (int p = 0; p < 4; p++)
        af[sk][p] = *(const bf16x8*)&tA[cur][(wr * 64 + p * 16 + lr) * 64 + koff];
#pragma unroll
      for (int q = 0; q < 4; q++)
        bfr[sk][q] = *(const bf16x8*)&tB[cur][(wc * 64 + q * 16 + lr) * 64 + koff];
    }
    asm volatile("s_waitcnt lgkmcnt(0)" ::: "memory");
    __builtin_amdgcn_sched_barrier(0);
    __builtin_amdgcn_s_setprio(1);
#pragma unroll
    for (int sk = 0; sk < 2; sk++)
#pragma unroll
      for (int p = 0; p < 4; p++)
#pragma unroll
        for (int q = 0; q < 4; q++)
          acc[p][q] = __builtin_amdgcn_mfma_f32_16x16x32_bf16(af[sk][p], bfr[sk][q], acc[p][q], 0, 0, 0);
    __builtin_amdgcn_s_setprio(0);
    __builtin_amdgcn_s_barrier();  // all reads of cur done -> buffer reusable
    cur = cur + 1; if (cur >= 3) cur = 0;
  }
#undef STAGE

  // ---- fused epilogue: agg = acc * rinv[row]  ->  out = relu(agg @ W + bias) ----
  bf16x8 wf[4][4];  // [q][ks]
#pragma unroll
  for (int q = 0; q < 4; q++)
#pragma unroll
    for (int ks = 0; ks < 4; ks++)
      wf[q][ks] = *(const bf16x8*)&Wt[(size_t)(wc * 64 + q * 16 + lr) * DIN + ks * 32 + lq * 8];

  // eps aliases the (now-dead) staging buffers: 128x136 bf16 = 34.8 KB <= tA's 48 KB
  unsigned short* eps = &tA[0][0];
#pragma unroll
  for (int p = 0; p < 4; p++) {
    float rv[4];
#pragma unroll
    for (int i = 0; i < 4; i++)
      rv[i] = rinv[m0 + wr * 64 + p * 16 + lq * 4 + i];
#pragma unroll
    for (int q = 0; q < 4; q++)
#pragma unroll
      for (int i = 0; i < 4; i++)
        eps[(wr * 64 + p * 16 + lq * 4 + i) * 136 + wc * 64 + q * 16 + lr] =
            f2bf(acc[p][q][i] * rv[i]);
  }
  __syncthreads();

  f32x4 acc2[4][4];
#pragma unroll
  for (int p = 0; p < 4; p++)
#pragma unroll
    for (int q = 0; q < 4; q++) acc2[p][q] = (f32x4){0.f, 0.f, 0.f, 0.f};

#pragma unroll
  for (int ks = 0; ks < 4; ks++) {
    bf16x8 a2[4];
#pragma unroll
    for (int p = 0; p < 4; p++)
      a2[p] = *(const bf16x8*)&eps[(wr * 64 + p * 16 + lr) * 136 + ks * 32 + lq * 8];
#pragma unroll
    for (int p = 0; p < 4; p++)
#pragma unroll
      for (int q = 0; q < 4; q++)
        acc2[p][q] = __builtin_amdgcn_mfma_f32_16x16x32_bf16(a2[p], wf[q][ks], acc2[p][q], 0, 0, 0);
  }

#pragma unroll
  for (int p = 0; p < 4; p++)
#pragma unroll
    for (int q = 0; q < 4; q++) {
      const int o = wc * 64 + q * 16 + lr;
      const float bb = bias[o];
#pragma unroll
      for (int i = 0; i < 4; i++) {
        const int n = m0 + wr * 64 + p * 16 + lq * 4 + i;
        if (n < NSEN)
          out[((size_t)b * NSEN + n) * DOUT + o] = fmaxf(acc2[p][q][i] + bb, 0.f);
      }
    }
}

// ---------------- launch ---------------------------------------------------------
extern "C" void kernel_launch(void* const* d_in, const int* in_sizes, int n_in,
                              void* d_out, int out_size, void* d_ws, size_t ws_size,
                              hipStream_t stream) {
  const float* x    = (const float*)d_in[0];
  const float* E1   = (const float*)d_in[1];
  const float* E2   = (const float*)d_in[2];
  const float* W    = (const float*)d_in[3];
  const float* bias = (const float*)d_in[4];
  float* out = (float*)d_out;

  char* ws = (char*)d_ws;
  // layout: adjp 33554432 | xpt 8388608 | Wt 32768 | rinv 16384  (~42 MiB)
  unsigned short* adjp = (unsigned short*)(ws);
  unsigned short* xpt  = (unsigned short*)(ws + 33554432);
  unsigned short* wt   = (unsigned short*)(ws + 33554432 + 8388608);
  float*          rinv = (float*)(ws + 33554432 + 8388608 + 32768);

  k_adj<<<dim3(NSEN / 16 + 1), dim3(256), 0, stream>>>(E1, E2, W, adjp, rinv, wt);
  k_xpt<<<dim3(NP / 64, DIN / 64, BATCH), dim3(256), 0, stream>>>(x, xpt);
  k_gemm1<<<dim3(NP / 128, BATCH), dim3(256), 0, stream>>>(adjp, xpt, wt, rinv, bias, out);
}

// Round 4
// 98.177 us; speedup vs baseline: 1.4897x; 1.2273x over previous
//
#include <hip/hip_runtime.h>
#include <hip/hip_bf16.h>

#define NSEN 4000
#define NP   4096
#define DIN  128
#define DOUT 128
#define EDIM 16
#define BATCH 8

typedef __attribute__((ext_vector_type(8))) short bf16x8;
typedef __attribute__((ext_vector_type(4))) float f32x4;

__device__ __forceinline__ unsigned short f2bf(float f) {
  unsigned int u = __float_as_uint(f);
  unsigned int r = (u + 0x7FFFu + ((u >> 16) & 1u)) >> 16;
  return (unsigned short)r;
}
__device__ __forceinline__ float bf2f(unsigned short s) {
  unsigned int u = ((unsigned int)s) << 16;
  return __uint_as_float(u);
}

__device__ __forceinline__ void gl_lds16(const void* g, void* l) {
  __builtin_amdgcn_global_load_lds((const __attribute__((address_space(1))) void*)g,
                                   (__attribute__((address_space(3))) void*)l, 16, 0, 0);
}

// ---------------- Kernel 1: P = exp(relu(E1 @ E2^T)) unnorm -> bf16; rinv = 1/rowsum
// MFMA with hi/lo bf16 split: dot ~= hi.hi + hi.lo + lo.hi (error ~1e-4, f32-grade).
// MFMA1: A=[hiA|hiA] x B=[hiB|loB] -> hiA.hiB + hiA.loB ; MFMA2: A=[loA|0] x same B -> loA.hiB
// Block 250 does the tiny W transpose instead.
__global__ __launch_bounds__(256) void k_adj(const float* __restrict__ E1,
                                             const float* __restrict__ E2,
                                             const float* __restrict__ W,
                                             unsigned short* __restrict__ adjp,
                                             float* __restrict__ rinv,
                                             unsigned short* __restrict__ Wt) {
  __shared__ float rsum[4][16];
  if (blockIdx.x == NSEN / 16) {
    for (int i = threadIdx.x; i < DIN * DOUT; i += 256) {
      int o = i >> 7, f = i & 127;
      Wt[i] = f2bf(W[(size_t)f * DOUT + o]);
    }
    return;
  }
  const int tid = threadIdx.x;
  const int lane = tid & 63, wv = tid >> 6;
  const int lr = lane & 15, lq = lane >> 4;
  const int n0 = blockIdx.x * 16;

  // A fragments from E1 rows n0..n0+15 (row = lr, k-halves via lq&1)
  float a[8];
  {
    const float* e1p = &E1[(size_t)(n0 + lr) * EDIM + (lq & 1) * 8];
    *(float4*)&a[0] = *(const float4*)e1p;
    *(float4*)&a[4] = *(const float4*)(e1p + 4);
  }
  bf16x8 af1, af2;
#pragma unroll
  for (int j = 0; j < 8; j++) {
    unsigned short hs = f2bf(a[j]);
    af1[j] = (short)hs;                       // hi for all lq (k<16 and k>=16 mirror)
    float lo = a[j] - bf2f(hs);
    af2[j] = (lq < 2) ? (short)f2bf(lo) : (short)0;  // lo on k<16, zero on k>=16
  }

  float rs[4] = {0.f, 0.f, 0.f, 0.f};
  for (int t = wv; t < NSEN / 16; t += 4) {
    const int m = t * 16 + lr;                 // B column (= E2 row)
    float bv[8];
    const float* e2p = &E2[(size_t)m * EDIM + (lq & 1) * 8];
    *(float4*)&bv[0] = *(const float4*)e2p;
    *(float4*)&bv[4] = *(const float4*)(e2p + 4);
    bf16x8 bfrag;
#pragma unroll
    for (int j = 0; j < 8; j++) {
      unsigned short hs = f2bf(bv[j]);
      if (lq < 2) bfrag[j] = (short)hs;                      // hi on k<16
      else        bfrag[j] = (short)f2bf(bv[j] - bf2f(hs));  // lo on k>=16
    }
    f32x4 c = (f32x4){0.f, 0.f, 0.f, 0.f};
    c = __builtin_amdgcn_mfma_f32_16x16x32_bf16(af1, bfrag, c, 0, 0, 0);
    c = __builtin_amdgcn_mfma_f32_16x16x32_bf16(af2, bfrag, c, 0, 0, 0);
    // C layout: col = lr (m), row = lq*4 + i
#pragma unroll
    for (int i = 0; i < 4; i++) {
      float p = __expf(fmaxf(c[i], 0.f));
      rs[i] += p;
      adjp[(size_t)(n0 + lq * 4 + i) * NP + t * 16 + lr] = f2bf(p);
    }
  }
  // zero-pad cols 4000..4095
  for (int i = tid; i < 16 * (NP - NSEN); i += 256) {
    int r = i / (NP - NSEN), c = i % (NP - NSEN);
    adjp[(size_t)(n0 + r) * NP + NSEN + c] = 0;
  }
  // reduce rowsums over the 16 cols (lr bits), then across waves
#pragma unroll
  for (int i = 0; i < 4; i++) {
    rs[i] += __shfl_xor(rs[i], 1, 64);
    rs[i] += __shfl_xor(rs[i], 2, 64);
    rs[i] += __shfl_xor(rs[i], 4, 64);
    rs[i] += __shfl_xor(rs[i], 8, 64);
  }
  if (lr == 0) {
#pragma unroll
    for (int i = 0; i < 4; i++) rsum[wv][lq * 4 + i] = rs[i];
  }
  __syncthreads();
  if (tid < 16)
    rinv[n0 + tid] = 1.0f / (rsum[0][tid] + rsum[1][tid] + rsum[2][tid] + rsum[3][tid]);
}

// ---------------- Kernel 2: xpt[b*128+f][m] = bf16(x[b][m][f]), cols m>=NSEN -> 0
__global__ __launch_bounds__(256) void k_xpt(const float* __restrict__ x,
                                             unsigned short* __restrict__ xpt) {
  __shared__ unsigned short tile[64][72];
  const int t = threadIdx.x;
  const int m0 = blockIdx.x * 64;
  const int f0 = blockIdx.y * 64;
  const int b  = blockIdx.z;
  const int f4 = t & 15, mrow = t >> 4;
#pragma unroll
  for (int rep = 0; rep < 4; rep++) {
    int ml = mrow + rep * 16;
    int m = m0 + ml;
    float4 v = make_float4(0.f, 0.f, 0.f, 0.f);
    if (m < NSEN) v = *(const float4*)&x[((size_t)b * NSEN + m) * DIN + f0 + f4 * 4];
    tile[f4*4+0][ml] = f2bf(v.x);
    tile[f4*4+1][ml] = f2bf(v.y);
    tile[f4*4+2][ml] = f2bf(v.z);
    tile[f4*4+3][ml] = f2bf(v.w);
  }
  __syncthreads();
  const int seg = t & 7, fl0 = t >> 3;
#pragma unroll
  for (int it = 0; it < 2; it++) {
    int fl = fl0 + it * 32;
    int j = b * DIN + f0 + fl;
    uint4 v = *(const uint4*)&tile[fl][seg * 8];
    *(uint4*)&xpt[(size_t)j * NP + m0 + seg * 8] = v;
  }
}

// ---------------- Kernel 3: fused  out = relu(((P @ x) * rinv) @ W + bias) ------
// 512 threads, 8 waves (4 row-slabs x 2 col-halves), each wave 32x64 output.
// BK=64, 2-buffer 64KB LDS, depth-1 prefetch, counted vmcnt, setprio, swizzled LDS.
__global__ __launch_bounds__(512, 2) void k_gemm1(const unsigned short* __restrict__ A,
                                                  const unsigned short* __restrict__ Bt,
                                                  const unsigned short* __restrict__ Wt,
                                                  const float* __restrict__ rinv,
                                                  const float* __restrict__ bias,
                                                  float* __restrict__ out) {
  __shared__ __align__(16) unsigned short smem[32768];  // 64 KB: A[2][8192] | B[2][8192]
  const int tid = threadIdx.x;
  const int lane = tid & 63, wv = tid >> 6;
  const int wr = wv >> 1, wc = wv & 1;     // 4 x 2 wave grid
  const int lr = lane & 15, lq = lane >> 4;
  const int m0 = blockIdx.x * 128;  // x-major: linear%8 = m-tile%8 -> m-cohort shares XCD L2
  const int b  = blockIdx.y;
  const int c0 = b * 128;
  unsigned short* tA0 = smem;
  unsigned short* tB0 = smem + 16384;

  f32x4 acc[2][4];
#pragma unroll
  for (int p = 0; p < 2; p++)
#pragma unroll
    for (int q = 0; q < 4; q++) acc[p][q] = (f32x4){0.f, 0.f, 0.f, 0.f};

  // 4 gl_lds16 per thread per STAGE (2 A + 2 B); source k-chunk pre-swizzled
#define STAGE(bufi, kb)                                                           \
  {                                                                               \
    _Pragma("unroll")                                                             \
    for (int s = 0; s < 2; s++) {                                                 \
      int idx = s * 512 + tid;                                                    \
      int row = idx >> 3;                                                         \
      int kc = ((idx & 7) ^ (row & 7)) << 3;                                      \
      gl_lds16(&A[(size_t)(m0 + row) * NP + (kb) + kc], &tA0[(bufi)*8192 + idx*8]); \
      gl_lds16(&Bt[(size_t)(c0 + row) * NP + (kb) + kc], &tB0[(bufi)*8192 + idx*8]); \
    }                                                                             \
  }

  STAGE(0, 0);

  for (int it = 0; it < 64; ++it) {
    const int cur = it & 1;
    if (it < 63) {
      STAGE(cur ^ 1, (it + 1) * 64);
      asm volatile("s_waitcnt vmcnt(4)" ::: "memory");  // cur's 4 landed; next 4 in flight
    } else {
      asm volatile("s_waitcnt vmcnt(0)" ::: "memory");
    }
    __builtin_amdgcn_s_barrier();  // all waves' cur tile staged

    bf16x8 af[2][2], bfr[2][4];
#pragma unroll
    for (int sk = 0; sk < 2; sk++) {
      const int koff = (sk * 32 + lq * 8) ^ ((lr & 7) << 3);
#pragma unroll
      for (int p = 0; p < 2; p++)
        af[sk][p] = *(const bf16x8*)&tA0[cur * 8192 + (wr * 32 + p * 16 + lr) * 64 + koff];
#pragma unroll
      for (int q = 0; q < 4; q++)
        bfr[sk][q] = *(const bf16x8*)&tB0[cur * 8192 + (wc * 64 + q * 16 + lr) * 64 + koff];
    }
    asm volatile("s_waitcnt lgkmcnt(0)" ::: "memory");
    __builtin_amdgcn_sched_barrier(0);
    __builtin_amdgcn_s_setprio(1);
#pragma unroll
    for (int sk = 0; sk < 2; sk++)
#pragma unroll
      for (int p = 0; p < 2; p++)
#pragma unroll
        for (int q = 0; q < 4; q++)
          acc[p][q] = __builtin_amdgcn_mfma_f32_16x16x32_bf16(af[sk][p], bfr[sk][q], acc[p][q], 0, 0, 0);
    __builtin_amdgcn_s_setprio(0);
    __builtin_amdgcn_s_barrier();  // cur fully consumed -> reusable
  }
#undef STAGE

  // ---- fused epilogue: agg = acc * rinv[row]  ->  out = relu(agg @ W + bias) ----
  bf16x8 wf[4][4];  // [q][ks]
#pragma unroll
  for (int q = 0; q < 4; q++)
#pragma unroll
    for (int ks = 0; ks < 4; ks++)
      wf[q][ks] = *(const bf16x8*)&Wt[(size_t)(wc * 64 + q * 16 + lr) * DIN + ks * 32 + lq * 8];

  // eps aliases dead staging LDS: 128x136 bf16 = 34.8 KB <= 64 KB
  unsigned short* eps = smem;
#pragma unroll
  for (int p = 0; p < 2; p++) {
    float rv[4];
#pragma unroll
    for (int i = 0; i < 4; i++)
      rv[i] = rinv[m0 + wr * 32 + p * 16 + lq * 4 + i];
#pragma unroll
    for (int q = 0; q < 4; q++)
#pragma unroll
      for (int i = 0; i < 4; i++)
        eps[(wr * 32 + p * 16 + lq * 4 + i) * 136 + wc * 64 + q * 16 + lr] =
            f2bf(acc[p][q][i] * rv[i]);
  }
  __syncthreads();

  f32x4 acc2[2][4];
#pragma unroll
  for (int p = 0; p < 2; p++)
#pragma unroll
    for (int q = 0; q < 4; q++) acc2[p][q] = (f32x4){0.f, 0.f, 0.f, 0.f};

#pragma unroll
  for (int ks = 0; ks < 4; ks++) {
    bf16x8 a2[2];
#pragma unroll
    for (int p = 0; p < 2; p++)
      a2[p] = *(const bf16x8*)&eps[(wr * 32 + p * 16 + lr) * 136 + ks * 32 + lq * 8];
#pragma unroll
    for (int p = 0; p < 2; p++)
#pragma unroll
      for (int q = 0; q < 4; q++)
        acc2[p][q] = __builtin_amdgcn_mfma_f32_16x16x32_bf16(a2[p], wf[q][ks], acc2[p][q], 0, 0, 0);
  }

#pragma unroll
  for (int p = 0; p < 2; p++)
#pragma unroll
    for (int q = 0; q < 4; q++) {
      const int o = wc * 64 + q * 16 + lr;
      const float bb = bias[o];
#pragma unroll
      for (int i = 0; i < 4; i++) {
        const int n = m0 + wr * 32 + p * 16 + lq * 4 + i;
        if (n < NSEN)
          out[((size_t)b * NSEN + n) * DOUT + o] = fmaxf(acc2[p][q][i] + bb, 0.f);
      }
    }
}

// ---------------- launch ---------------------------------------------------------
extern "C" void kernel_launch(void* const* d_in, const int* in_sizes, int n_in,
                              void* d_out, int out_size, void* d_ws, size_t ws_size,
                              hipStream_t stream) {
  const float* x    = (const float*)d_in[0];
  const float* E1   = (const float*)d_in[1];
  const float* E2   = (const float*)d_in[2];
  const float* W    = (const float*)d_in[3];
  const float* bias = (const float*)d_in[4];
  float* out = (float*)d_out;

  char* ws = (char*)d_ws;
  // layout: adjp 33554432 | xpt 8388608 | Wt 32768 | rinv 16384  (~42 MiB)
  unsigned short* adjp = (unsigned short*)(ws);
  unsigned short* xpt  = (unsigned short*)(ws + 33554432);
  unsigned short* wt   = (unsigned short*)(ws + 33554432 + 8388608);
  float*          rinv = (float*)(ws + 33554432 + 8388608 + 32768);

  k_adj<<<dim3(NSEN / 16 + 1), dim3(256), 0, stream>>>(E1, E2, W, adjp, rinv, wt);
  k_xpt<<<dim3(NP / 64, DIN / 64, BATCH), dim3(256), 0, stream>>>(x, xpt);
  k_gemm1<<<dim3(NP / 128, BATCH), dim3(512), 0, stream>>>(adjp, xpt, wt, rinv, bias, out);
}

// Round 5
// 81.536 us; speedup vs baseline: 1.7938x; 1.2041x over previous
//
#include <hip/hip_runtime.h>
#include <hip/hip_bf16.h>

#define NSEN 4000
#define NP   4096
#define DIN  128
#define DOUT 128
#define EDIM 16
#define BATCH 8

typedef __attribute__((ext_vector_type(8))) short bf16x8;
typedef __attribute__((ext_vector_type(4))) float f32x4;

__device__ __forceinline__ unsigned short f2bf(float f) {
  unsigned int u = __float_as_uint(f);
  unsigned int r = (u + 0x7FFFu + ((u >> 16) & 1u)) >> 16;
  return (unsigned short)r;
}
__device__ __forceinline__ float bf2f(unsigned short s) {
  unsigned int u = ((unsigned int)s) << 16;
  return __uint_as_float(u);
}

__device__ __forceinline__ void gl_lds16(const void* g, void* l) {
  __builtin_amdgcn_global_load_lds((const __attribute__((address_space(1))) void*)g,
                                   (__attribute__((address_space(3))) void*)l, 16, 0, 0);
}

// ---------------- Kernel 1: P = exp(relu(E1 @ E2^T)) unnorm -> bf16; rinv = 1/rowsum
// MFMA hi/lo split (see R4). 512 threads, 8 waves. Block 250 transposes W.
__global__ __launch_bounds__(512) void k_adj(const float* __restrict__ E1,
                                             const float* __restrict__ E2,
                                             const float* __restrict__ W,
                                             unsigned short* __restrict__ adjp,
                                             float* __restrict__ rinv,
                                             unsigned short* __restrict__ Wt) {
  __shared__ float rsum[8][16];
  if (blockIdx.x == NSEN / 16) {
    for (int i = threadIdx.x; i < DIN * DOUT; i += 512) {
      int o = i >> 7, f = i & 127;
      Wt[i] = f2bf(W[(size_t)f * DOUT + o]);
    }
    return;
  }
  const int tid = threadIdx.x;
  const int lane = tid & 63, wv = tid >> 6;
  const int lr = lane & 15, lq = lane >> 4;
  const int n0 = blockIdx.x * 16;

  float a[8];
  {
    const float* e1p = &E1[(size_t)(n0 + lr) * EDIM + (lq & 1) * 8];
    *(float4*)&a[0] = *(const float4*)e1p;
    *(float4*)&a[4] = *(const float4*)(e1p + 4);
  }
  bf16x8 af1, af2;
#pragma unroll
  for (int j = 0; j < 8; j++) {
    unsigned short hs = f2bf(a[j]);
    af1[j] = (short)hs;
    float lo = a[j] - bf2f(hs);
    af2[j] = (lq < 2) ? (short)f2bf(lo) : (short)0;
  }

  float rs[4] = {0.f, 0.f, 0.f, 0.f};
  for (int t = wv; t < NSEN / 16; t += 8) {
    const int m = t * 16 + lr;
    float bv[8];
    const float* e2p = &E2[(size_t)m * EDIM + (lq & 1) * 8];
    *(float4*)&bv[0] = *(const float4*)e2p;
    *(float4*)&bv[4] = *(const float4*)(e2p + 4);
    bf16x8 bfrag;
#pragma unroll
    for (int j = 0; j < 8; j++) {
      unsigned short hs = f2bf(bv[j]);
      if (lq < 2) bfrag[j] = (short)hs;
      else        bfrag[j] = (short)f2bf(bv[j] - bf2f(hs));
    }
    f32x4 c = (f32x4){0.f, 0.f, 0.f, 0.f};
    c = __builtin_amdgcn_mfma_f32_16x16x32_bf16(af1, bfrag, c, 0, 0, 0);
    c = __builtin_amdgcn_mfma_f32_16x16x32_bf16(af2, bfrag, c, 0, 0, 0);
#pragma unroll
    for (int i = 0; i < 4; i++) {
      float p = __expf(fmaxf(c[i], 0.f));
      rs[i] += p;
      adjp[(size_t)(n0 + lq * 4 + i) * NP + t * 16 + lr] = f2bf(p);
    }
  }
  for (int i = tid; i < 16 * (NP - NSEN); i += 512) {
    int r = i / (NP - NSEN), c = i % (NP - NSEN);
    adjp[(size_t)(n0 + r) * NP + NSEN + c] = 0;
  }
#pragma unroll
  for (int i = 0; i < 4; i++) {
    rs[i] += __shfl_xor(rs[i], 1, 64);
    rs[i] += __shfl_xor(rs[i], 2, 64);
    rs[i] += __shfl_xor(rs[i], 4, 64);
    rs[i] += __shfl_xor(rs[i], 8, 64);
  }
  if (lr == 0) {
#pragma unroll
    for (int i = 0; i < 4; i++) rsum[wv][lq * 4 + i] = rs[i];
  }
  __syncthreads();
  if (tid < 16) {
    float s = 0.f;
#pragma unroll
    for (int w = 0; w < 8; w++) s += rsum[w][tid];
    rinv[n0 + tid] = 1.0f / s;
  }
}

// ---------------- Kernel 2: xpt[b*128+f][m] = bf16(x[b][m][f]), cols m>=NSEN -> 0
__global__ __launch_bounds__(256) void k_xpt(const float* __restrict__ x,
                                             unsigned short* __restrict__ xpt) {
  __shared__ unsigned short tile[64][72];
  const int t = threadIdx.x;
  const int m0 = blockIdx.x * 64;
  const int f0 = blockIdx.y * 64;
  const int b  = blockIdx.z;
  const int f4 = t & 15, mrow = t >> 4;
#pragma unroll
  for (int rep = 0; rep < 4; rep++) {
    int ml = mrow + rep * 16;
    int m = m0 + ml;
    float4 v = make_float4(0.f, 0.f, 0.f, 0.f);
    if (m < NSEN) v = *(const float4*)&x[((size_t)b * NSEN + m) * DIN + f0 + f4 * 4];
    tile[f4*4+0][ml] = f2bf(v.x);
    tile[f4*4+1][ml] = f2bf(v.y);
    tile[f4*4+2][ml] = f2bf(v.z);
    tile[f4*4+3][ml] = f2bf(v.w);
  }
  __syncthreads();
  const int seg = t & 7, fl0 = t >> 3;
#pragma unroll
  for (int it = 0; it < 2; it++) {
    int fl = fl0 + it * 32;
    int j = b * DIN + f0 + fl;
    uint4 v = *(const uint4*)&tile[fl][seg * 8];
    *(uint4*)&xpt[(size_t)j * NP + m0 + seg * 8] = v;
  }
}

// ---------------- Kernel 3: fused  out = relu(((P @ x) * rinv) @ W + bias) ------
// BM=64, BN=128: grid 512 -> 2 INDEPENDENT blocks/CU (barrier decoupling).
// 256 thr = 4 waves (2Mx2N), wave tile 32x64. BK=64, 3-buffer depth-2 prefetch,
// counted vmcnt(12), setprio, XOR-swizzled LDS via pre-swizzled source.
__global__ __launch_bounds__(256, 2) void k_gemm1(const unsigned short* __restrict__ A,
                                                  const unsigned short* __restrict__ Bt,
                                                  const unsigned short* __restrict__ Wt,
                                                  const float* __restrict__ rinv,
                                                  const float* __restrict__ bias,
                                                  float* __restrict__ out) {
  __shared__ __align__(16) unsigned short smem[36864];  // 72 KB: A 3x4096 | B 3x8192
  const int tid = threadIdx.x;
  const int lane = tid & 63, wv = tid >> 6;
  const int wr = wv >> 1, wc = wv & 1;     // 2 x 2 wave grid
  const int lr = lane & 15, lq = lane >> 4;
  const int m0 = blockIdx.x * 64;   // x%8 -> XCD: 8 batch-blocks of one A-panel share L2
  const int b  = blockIdx.y;
  const int c0 = b * 128;
  unsigned short* tA0 = smem;           // 3 * 4096
  unsigned short* tB0 = smem + 12288;   // 3 * 8192

  f32x4 acc[2][4];
#pragma unroll
  for (int p = 0; p < 2; p++)
#pragma unroll
    for (int q = 0; q < 4; q++) acc[p][q] = (f32x4){0.f, 0.f, 0.f, 0.f};

  // A: 512 16B-chunks (2/thread), B: 1024 (4/thread); 6 gl_lds16 per thread
#define STAGE(bufi, kb)                                                              \
  {                                                                                  \
    _Pragma("unroll")                                                                \
    for (int s = 0; s < 2; s++) {                                                    \
      int idx = s * 256 + tid;                                                       \
      int row = idx >> 3;                                                            \
      int kc = ((idx & 7) ^ (row & 7)) << 3;                                         \
      gl_lds16(&A[(size_t)(m0 + row) * NP + (kb) + kc], &tA0[(bufi)*4096 + idx*8]);  \
    }                                                                                \
    _Pragma("unroll")                                                                \
    for (int s = 0; s < 4; s++) {                                                    \
      int idx = s * 256 + tid;                                                       \
      int row = idx >> 3;                                                            \
      int kc = ((idx & 7) ^ (row & 7)) << 3;                                         \
      gl_lds16(&Bt[(size_t)(c0 + row) * NP + (kb) + kc], &tB0[(bufi)*8192 + idx*8]); \
    }                                                                                \
  }

  STAGE(0, 0);
  STAGE(1, 64);

  int cur = 0;
  for (int it = 0; it < 64; ++it) {
    if (it < 62) {
      int nb = cur + 2; if (nb >= 3) nb -= 3;
      STAGE(nb, (it + 2) * 64);
      asm volatile("s_waitcnt vmcnt(12)" ::: "memory");  // cur's 6 landed; 12 in flight
    } else if (it == 62) {
      asm volatile("s_waitcnt vmcnt(6)" ::: "memory");
    } else {
      asm volatile("s_waitcnt vmcnt(0)" ::: "memory");
    }
    __builtin_amdgcn_s_barrier();

    bf16x8 af[2][2], bfr[2][4];
#pragma unroll
    for (int sk = 0; sk < 2; sk++) {
      const int koff = (sk * 32 + lq * 8) ^ ((lr & 7) << 3);
#pragma unroll
      for (int p = 0; p < 2; p++)
        af[sk][p] = *(const bf16x8*)&tA0[cur * 4096 + (wr * 32 + p * 16 + lr) * 64 + koff];
#pragma unroll
      for (int q = 0; q < 4; q++)
        bfr[sk][q] = *(const bf16x8*)&tB0[cur * 8192 + (wc * 64 + q * 16 + lr) * 64 + koff];
    }
    asm volatile("s_waitcnt lgkmcnt(0)" ::: "memory");
    __builtin_amdgcn_sched_barrier(0);
    __builtin_amdgcn_s_setprio(1);
#pragma unroll
    for (int sk = 0; sk < 2; sk++)
#pragma unroll
      for (int p = 0; p < 2; p++)
#pragma unroll
        for (int q = 0; q < 4; q++)
          acc[p][q] = __builtin_amdgcn_mfma_f32_16x16x32_bf16(af[sk][p], bfr[sk][q], acc[p][q], 0, 0, 0);
    __builtin_amdgcn_s_setprio(0);
    __builtin_amdgcn_s_barrier();
    cur = cur + 1; if (cur >= 3) cur = 0;
  }
#undef STAGE

  // ---- fused epilogue: agg = acc * rinv[row]  ->  out = relu(agg @ W + bias) ----
  bf16x8 wf[4][4];  // [q][ks]
#pragma unroll
  for (int q = 0; q < 4; q++)
#pragma unroll
    for (int ks = 0; ks < 4; ks++)
      wf[q][ks] = *(const bf16x8*)&Wt[(size_t)(wc * 64 + q * 16 + lr) * DIN + ks * 32 + lq * 8];

  // eps aliases dead staging LDS: 64x136 bf16 = 17.4 KB
  unsigned short* eps = smem;
#pragma unroll
  for (int p = 0; p < 2; p++) {
    float rv[4];
#pragma unroll
    for (int i = 0; i < 4; i++)
      rv[i] = rinv[m0 + wr * 32 + p * 16 + lq * 4 + i];
#pragma unroll
    for (int q = 0; q < 4; q++)
#pragma unroll
      for (int i = 0; i < 4; i++)
        eps[(wr * 32 + p * 16 + lq * 4 + i) * 136 + wc * 64 + q * 16 + lr] =
            f2bf(acc[p][q][i] * rv[i]);
  }
  __syncthreads();

  f32x4 acc2[2][4];
#pragma unroll
  for (int p = 0; p < 2; p++)
#pragma unroll
    for (int q = 0; q < 4; q++) acc2[p][q] = (f32x4){0.f, 0.f, 0.f, 0.f};

#pragma unroll
  for (int ks = 0; ks < 4; ks++) {
    bf16x8 a2[2];
#pragma unroll
    for (int p = 0; p < 2; p++)
      a2[p] = *(const bf16x8*)&eps[(wr * 32 + p * 16 + lr) * 136 + ks * 32 + lq * 8];
#pragma unroll
    for (int p = 0; p < 2; p++)
#pragma unroll
      for (int q = 0; q < 4; q++)
        acc2[p][q] = __builtin_amdgcn_mfma_f32_16x16x32_bf16(a2[p], wf[q][ks], acc2[p][q], 0, 0, 0);
  }

#pragma unroll
  for (int p = 0; p < 2; p++)
#pragma unroll
    for (int q = 0; q < 4; q++) {
      const int o = wc * 64 + q * 16 + lr;
      const float bb = bias[o];
#pragma unroll
      for (int i = 0; i < 4; i++) {
        const int n = m0 + wr * 32 + p * 16 + lq * 4 + i;
        if (n < NSEN)
          out[((size_t)b * NSEN + n) * DOUT + o] = fmaxf(acc2[p][q][i] + bb, 0.f);
      }
    }
}

// ---------------- launch ---------------------------------------------------------
extern "C" void kernel_launch(void* const* d_in, const int* in_sizes, int n_in,
                              void* d_out, int out_size, void* d_ws, size_t ws_size,
                              hipStream_t stream) {
  const float* x    = (const float*)d_in[0];
  const float* E1   = (const float*)d_in[1];
  const float* E2   = (const float*)d_in[2];
  const float* W    = (const float*)d_in[3];
  const float* bias = (const float*)d_in[4];
  float* out = (float*)d_out;

  char* ws = (char*)d_ws;
  // layout: adjp 33554432 | xpt 8388608 | Wt 32768 | rinv 16384  (~42 MiB)
  unsigned short* adjp = (unsigned short*)(ws);
  unsigned short* xpt  = (unsigned short*)(ws + 33554432);
  unsigned short* wt   = (unsigned short*)(ws + 33554432 + 8388608);
  float*          rinv = (float*)(ws + 33554432 + 8388608 + 32768);

  k_adj<<<dim3(NSEN / 16 + 1), dim3(512), 0, stream>>>(E1, E2, W, adjp, rinv, wt);
  k_xpt<<<dim3(NP / 64, DIN / 64, BATCH), dim3(256), 0, stream>>>(x, xpt);
  k_gemm1<<<dim3(NP / 64, BATCH), dim3(256), 0, stream>>>(adjp, xpt, wt, rinv, bias, out);
}